// Round 8
// baseline (42.114 us; speedup 1.0000x reference)
//
#include <hip/hip_runtime.h>
#include <hip/hip_bf16.h>

// Oja scan, reformulated. G[b][n][t] = row_n . x_t for n in [0,1088):
// rows 0..1023 = W0 rows, rows 1024..1087 = X rows (=> S = X X^T).
// Scan: exact projected Oja recurrence on u[j] = W_t . x_j:
//   y_t = sigmoid(u[t]);  u <- (1-lr*y^2)*u + (lr*y)*S[t,:]
// R8: (gemm) burst-stage A: 16 float4 loads issued back-to-back into regs
//     (restores MLP the load->cvt->ds_write interleave was killing), then
//     cvt+ds_write burst. (scan) 2 rows per wave (interleaved chains, shared
//     S-read), raw v_exp_f32 sigmoid, XCD-aligned block->batch mapping.

#define BB 8
#define TT 64
#define NI 1024
#define NO 1024
#define NTOT 1088            // 1024 W rows + 64 X rows
#define NTILES 68            // NTOT/16
#define PADBF 1032           // LDS row stride in bf16 (1024 + 8)

typedef __attribute__((ext_vector_type(8))) short bf16x8;
typedef __attribute__((ext_vector_type(4))) float f32x4;

__device__ __forceinline__ short f2bf(float f) {
    __hip_bfloat16 h = __float2bfloat16(f);
    return __builtin_bit_cast(short, h);
}

// ---------- Kernel 0: X (f32) -> Xb16 (bf16), 524288 elements ----------
__global__ __launch_bounds__(256)
void xcvt_kernel(const float* __restrict__ X, ushort* __restrict__ Xb16)
{
    const int i = blockIdx.x * 256 + threadIdx.x;   // float4 index, 131072 total
    const float4 v = *reinterpret_cast<const float4*>(X + (size_t)i * 4);
    short4 s;
    s.x = f2bf(v.x); s.y = f2bf(v.y); s.z = f2bf(v.z); s.w = f2bf(v.w);
    *reinterpret_cast<short4*>(Xb16 + (size_t)i * 4) = s;
}

// ---------- Kernel 1: G[b][n][t] via MFMA, bf16 LDS A panel ----------
// Block: 256 thr = 4 waves; one 16-row n-tile; wave w owns t-tile w*16.
__global__ __launch_bounds__(256, 4)
void gemm_kernel(const float* __restrict__ X, const float* __restrict__ W0,
                 const ushort* __restrict__ Xb16, float* __restrict__ G)
{
    __shared__ ushort As[16 * PADBF];   // 33,024 B

    const int tid  = threadIdx.x;
    const int lane = tid & 63;
    const int wave = tid >> 6;
    const int b  = blockIdx.x & 7;       // blockIdx%8 = batch -> XCD-local X
    const int nt = blockIdx.x >> 3;
    const int n0 = nt * 16;
    const int t0 = wave * 16;

    const int r  = lane & 15;            // row within tile
    const int kb = lane >> 4;            // k-block 0..3 (8 k's each)

    const float* __restrict__ Abase =
        (n0 < NO) ? (W0 + ((size_t)b * NO + n0) * NI)
                  : (X + ((size_t)b * TT + (n0 - NO)) * NI);

    // ---- stage: burst-load 16 rows (16 B/thread each, all in flight),
    //      then cvt+ds_write burst. Each j: 4 KB contiguous per block. ----
    float4 v[16];
#pragma unroll
    for (int j = 0; j < 16; ++j)
        v[j] = *reinterpret_cast<const float4*>(Abase + (size_t)j * NI + tid * 4);
#pragma unroll
    for (int j = 0; j < 16; ++j) {
        short4 s;
        s.x = f2bf(v[j].x); s.y = f2bf(v[j].y); s.z = f2bf(v[j].z); s.w = f2bf(v[j].w);
        *reinterpret_cast<short4*>(&As[j * PADBF + tid * 4]) = s;
    }
    __syncthreads();

    // ---- MFMA loop: pure ds_read_b128 + 16B global B + MFMA ----
    const ushort* __restrict__ Bbase =
        Xb16 + ((size_t)b * TT + t0 + r) * NI + kb * 8;
    const ushort* __restrict__ Ap = &As[r * PADBF + kb * 8];

    f32x4 acc = {0.f, 0.f, 0.f, 0.f};
#pragma unroll 8
    for (int kk = 0; kk < 32; ++kk) {
        const bf16x8 a  = *reinterpret_cast<const bf16x8*>(Ap + kk * 32);
        const bf16x8 bv = *reinterpret_cast<const bf16x8*>(Bbase + kk * 32);
        acc = __builtin_amdgcn_mfma_f32_16x16x32_bf16(a, bv, acc, 0, 0, 0);
    }

    // D layout: col t = lane&15, row n = (lane>>4)*4 + rr   [m89-verified]
    const int tcol = lane & 15;
    const int mrow = (lane >> 4) * 4;
#pragma unroll
    for (int rr = 0; rr < 4; ++rr)
        G[((size_t)b * NTOT + n0 + mrow + rr) * TT + t0 + tcol] = acc[rr];
}

// ---------- Kernel 2: projected-Oja scan, 2 rows per wave ----------
// 512 blocks x 512 thr; block = (batch b = blockIdx&7, 16 o-rows).
__global__ __launch_bounds__(512, 4)
void scan_kernel(const float* __restrict__ G, float* __restrict__ out)
{
    __shared__ float Sl[TT][TT];        // 16 KB: S[b]
    __shared__ float ybuf[16][TT + 1];  // 16 rows' y trajectories (padded)

    const int tid  = threadIdx.x;
    const int lane = tid & 63;
    const int wave = tid >> 6;
    const int b  = blockIdx.x & 7;       // XCD-aligned with gemm's G[b] writes
    const int o0 = (blockIdx.x >> 3) * 16;

    // stage S[b] = G rows 1024..1087 (4096 contiguous floats)
    {
        const float4* __restrict__ src =
            reinterpret_cast<const float4*>(G + ((size_t)b * NTOT + NO) * TT);
        float4* dst = reinterpret_cast<float4*>(&Sl[0][0]);
        dst[tid]       = src[tid];
        dst[tid + 512] = src[tid + 512];
    }

    // two rows per wave: r0, r1 (independent chains, shared S)
    const int r0 = o0 + wave * 2;
    float u0 = G[((size_t)b * NTOT + r0) * TT + lane];
    float u1 = G[((size_t)b * NTOT + r0 + 1) * TT + lane];

    __syncthreads();

    const float lr = 1.0f / 1024.0f;
    const float L2E = 1.44269504f;       // log2(e)
    float y0s = 0.0f, y1s = 0.0f;
    float srow = Sl[0][lane];
#pragma unroll
    for (int t = 0; t < TT; ++t) {
        const float srow_next = (t + 1 < TT) ? Sl[t + 1][lane] : 0.0f;
        const float sg0 = __int_as_float(__builtin_amdgcn_readlane(__float_as_int(u0), t));
        const float sg1 = __int_as_float(__builtin_amdgcn_readlane(__float_as_int(u1), t));
        const float e0 = __builtin_amdgcn_exp2f(sg0 * -L2E);   // exp(-sg0)
        const float e1 = __builtin_amdgcn_exp2f(sg1 * -L2E);
        const float y0 = __builtin_amdgcn_rcpf(1.0f + e0);
        const float y1 = __builtin_amdgcn_rcpf(1.0f + e1);
        y0s = (lane == t) ? y0 : y0s;
        y1s = (lane == t) ? y1 : y1s;
        const float c20 = lr * y0, c21 = lr * y1;
        const float c10 = fmaf(-c20, y0, 1.0f);
        const float c11 = fmaf(-c21, y1, 1.0f);
        u0 = fmaf(c10, u0, c20 * srow);
        u1 = fmaf(c11, u1, c21 * srow);
        srow = srow_next;
    }

    ybuf[wave * 2][lane]     = y0s;      // lane = t
    ybuf[wave * 2 + 1][lane] = y1s;
    __syncthreads();

    // coalesced store: out[b][t][o0+oo], 16 consecutive o per t
    const int oo = tid & 15;             // 0..15
    const int t2 = tid >> 4;             // 0..31
#pragma unroll
    for (int q = 0; q < 2; ++q) {
        const int t = t2 * 2 + q;
        out[(size_t)b * TT * NO + (size_t)t * NO + o0 + oo] = ybuf[oo][t];
    }
}

extern "C" void kernel_launch(void* const* d_in, const int* in_sizes, int n_in,
                              void* d_out, int out_size, void* d_ws, size_t ws_size,
                              hipStream_t stream) {
    const float* X  = (const float*)d_in[0];   // [8][64][1024]
    const float* W0 = (const float*)d_in[1];   // [8][1024][1024]
    float* out = (float*)d_out;                // [8][64][1024]

    float*  G    = (float*)d_ws;                          // [8][1088][64] = 2,228,224 B
    ushort* Xb16 = (ushort*)((char*)d_ws + 2228224);      // [8][64][1024] bf16 = 1 MB

    xcvt_kernel<<<512, 256, 0, stream>>>(X, Xb16);
    gemm_kernel<<<BB * NTILES, 256, 0, stream>>>(X, W0, Xb16, G);
    scan_kernel<<<512, 512, 0, stream>>>(G, out);
}